// Round 17
// baseline (2240.668 us; speedup 1.0000x reference)
//
#include <hip/hip_runtime.h>

#define H  64
#define TT 512
#define BB 512
#define CSTR 80    // hbuf chain stride in halves
#define UCH 8      // consumer chunk (steps); producer builds chunk c+2 during c
#define NBUF 3     // xp triple buffer: read c%3, write (c+2)%3 -> disjoint
#define XSTR 260   // xp row stride in halves (520B: 8B-aligned rows, bank-rotated)

typedef _Float16 half8 __attribute__((ext_vector_type(8)));
typedef _Float16 half4 __attribute__((ext_vector_type(4)));
typedef float    f32x4 __attribute__((ext_vector_type(4)));

__device__ __forceinline__ float frcp(float x) { return __builtin_amdgcn_rcpf(x); }
__device__ __forceinline__ float sigm(float x) { return frcp(1.f + __expf(-x)); }
__device__ __forceinline__ float tanh_fast(float x) { return 1.f - 2.f * frcp(__expf(2.f * x) + 1.f); }

// ---------------------------------------------------------------------------
// xpad: [B*T][32] fp16, cols 0..3 = x, cols 4..31 = 0.
// ---------------------------------------------------------------------------
__global__ __launch_bounds__(256) void xpad_prep(const float* __restrict__ x,
                                                 _Float16* __restrict__ xpad) {
    int gid = blockIdx.x * 256 + threadIdx.x;
    int row = gid >> 2, q = gid & 3;
    half8 v = {0,0,0,0,0,0,0,0};
    if (q == 0) {
        float4 xv = ((const float4*)x)[row];
        v[0] = (_Float16)xv.x; v[1] = (_Float16)xv.y;
        v[2] = (_Float16)xv.z; v[3] = (_Float16)xv.w;
    }
    *(half8*)(xpad + (size_t)row * 32 + q * 8) = v;
}

// ---------------------------------------------------------------------------
// Layer 0: 512 thr = 8 waves. Waves 0-3: C=4 recurrence (no lane replication:
// col m -> chain (m&1)|((m>>3)<<1)). Waves 4-7: x-GEMM producer, builds chunk
// c+2 into xp[(c+2)%3] while consumers run chunk c. One barrier per step.
// ---------------------------------------------------------------------------
__global__ __launch_bounds__(512, 2) void lstm_l0(
    const _Float16* __restrict__ xpad,
    const float* __restrict__ WihF, const float* __restrict__ WhhF, const float* __restrict__ bF,
    const float* __restrict__ WihB, const float* __restrict__ WhhB, const float* __restrict__ bB,
    _Float16* __restrict__ out0)
{
    const int dir = blockIdx.x & 1;
    const int b0  = (blockIdx.x >> 1) * 4;
    const int tid = threadIdx.x;
    const int wv = tid >> 6, l = tid & 63, m = l & 15, q = l >> 4;
    const bool isCons = (wv < 4);

    const float* Wih = dir ? WihB : WihF;
    const float* Whh = dir ? WhhB : WhhF;
    const float* bia = dir ? bB   : bF;

    __shared__ __align__(16) _Float16 xp[NBUF][4][UCH][XSTR];   // 49.9 KB
    __shared__ _Float16 hbuf[2][4][CSTR];                       // 1.28 KB
    for (int i = tid; i < (2 * 4 * CSTR) / 2; i += 512) ((unsigned int*)hbuf)[i] = 0u;

    // ---- consumer setup ----
    const int w   = wv;
    const int ch  = (m & 1) | (((m >> 3) & 1) << 1);
    const int ubo = (m >> 1) & 3;
    const int uo  = w * 16 + ubo * 4 + q;
    half8 Ah[4][2];
    // ---- producer setup ----
    const int pw = wv - 4;
    half8 Bg[4];
    float bvj[4];

    if (isCons) {
#pragma unroll
        for (int ub = 0; ub < 4; ++ub) {
            const int wrow = (m & 3) * 64 + (w * 16 + ub * 4 + (m >> 2));
#pragma unroll
            for (int s2 = 0; s2 < 2; ++s2) {
                const float* src = Whh + wrow * 64 + s2 * 32 + q * 8;
                half8 tmp;
#pragma unroll
                for (int j = 0; j < 8; ++j) tmp[j] = (_Float16)src[j];
                Ah[ub][s2] = tmp;
            }
        }
    } else {
#pragma unroll
        for (int j = 0; j < 4; ++j) {
            const int n  = pw * 64 + j * 16 + m;
            const int gr = (n & 3) * 64 + (n >> 2);
            bvj[j] = bia[gr];
            half8 tmp;
#pragma unroll
            for (int jj = 0; jj < 8; ++jj) {
                int k = q * 8 + jj;
                tmp[jj] = (k < 4) ? (_Float16)Wih[gr * 4 + k] : (_Float16)0.f;
            }
            Bg[j] = tmp;
        }
        // prologue: produce chunks 0 and 1
        half8 pa;
#pragma unroll
        for (int cb = 0; cb < 2; ++cb) {
            for (int un = 0; un < 16; ++un) {
                int cc = un >> 2, j = un & 3;
                if (j == 0) {
                    int step = cb * UCH + (m & 7);
                    int tA = dir ? (TT - 1 - step) : step;
                    pa = *(const half8*)(xpad + ((size_t)(b0 + cc) * TT + tA) * 32 + q * 8);
                }
                f32x4 acc = {bvj[j], bvj[j], bvj[j], bvj[j]};
                acc = __builtin_amdgcn_mfma_f32_16x16x32_f16(pa, Bg[j], acc, 0, 0, 0);
                if (q < 2)
#pragma unroll
                    for (int i = 0; i < 4; ++i)
                        xp[cb][cc][q * 4 + i][pw * 64 + j * 16 + m] = (_Float16)acc[i];
            }
        }
    }
    __syncthreads();

    float c = 0.f;
    int p = 0;
    half4 xpre;
    half8 pa;

    for (int it = 0; it < TT; ++it) {
        if (isCons) {
            const int cck = it >> 3, u = it & 7;
            half4 xvh = (u == 0) ? *(const half4*)&xp[cck % 3][ch][0][uo * 4] : xpre;
            if (u < 7) xpre = *(const half4*)&xp[cck % 3][ch][u + 1][uo * 4];
            f32x4 cin = {(float)xvh[0], (float)xvh[1], (float)xvh[2], (float)xvh[3]};

            half8 ah0 = *(const half8*)&hbuf[p][ch][q * 8];
            half8 ah1 = *(const half8*)&hbuf[p][ch][32 + q * 8];

            f32x4 g_own;
#pragma unroll
            for (int ub = 0; ub < 4; ++ub) {
                f32x4 a = __builtin_amdgcn_mfma_f32_16x16x32_f16(Ah[ub][0], ah0, cin, 0, 0, 0);
                a       = __builtin_amdgcn_mfma_f32_16x16x32_f16(Ah[ub][1], ah1, a, 0, 0, 0);
                if (ub == ubo) g_own = a;
            }

            float e_i = sigm(g_own[0]), e_f = sigm(g_own[1]);
            float e_g = tanh_fast(g_own[2]), e_o = sigm(g_own[3]);
            c = e_f * c + e_i * e_g;
            float hh = e_o * tanh_fast(c);

            const int tg = dir ? (TT - 1 - it) : it;
            out0[((size_t)(b0 + ch) * TT + tg) * 128 + dir * 64 + uo] = (_Float16)hh;
            hbuf[p ^ 1][ch][uo] = (_Float16)hh;
            p ^= 1;
        } else {
            const int cb = (it >> 3) + 2, s = it & 7;
            if (cb < TT / UCH) {
#pragma unroll
                for (int t2 = 0; t2 < 2; ++t2) {
                    int un = s * 2 + t2;
                    int cc = un >> 2, j = un & 3;
                    if (j == 0) {
                        int step = cb * UCH + (m & 7);
                        int tA = dir ? (TT - 1 - step) : step;
                        pa = *(const half8*)(xpad + ((size_t)(b0 + cc) * TT + tA) * 32 + q * 8);
                    }
                    f32x4 acc = {bvj[j], bvj[j], bvj[j], bvj[j]};
                    acc = __builtin_amdgcn_mfma_f32_16x16x32_f16(pa, Bg[j], acc, 0, 0, 0);
                    if (q < 2)
#pragma unroll
                        for (int i = 0; i < 4; ++i)
                            xp[cb % 3][cc][q * 4 + i][pw * 64 + j * 16 + m] = (_Float16)acc[i];
                }
            }
        }
        __syncthreads();
    }
}

// ---------------------------------------------------------------------------
// Layer 1: same structure; producer K = 128 (4 MFMA slices), reads out0.
// ---------------------------------------------------------------------------
__global__ __launch_bounds__(512, 2) void lstm_l1(
    const _Float16* __restrict__ out0,
    const float* __restrict__ WihF, const float* __restrict__ WhhF, const float* __restrict__ bF,
    const float* __restrict__ WihB, const float* __restrict__ WhhB, const float* __restrict__ bB,
    float* __restrict__ pooled)
{
    const int dir = blockIdx.x & 1;
    const int b0  = (blockIdx.x >> 1) * 4;
    const int tid = threadIdx.x;
    const int wv = tid >> 6, l = tid & 63, m = l & 15, q = l >> 4;
    const bool isCons = (wv < 4);

    const float* Wih = dir ? WihB : WihF;
    const float* Whh = dir ? WhhB : WhhF;
    const float* bia = dir ? bB   : bF;

    __shared__ __align__(16) _Float16 xp[NBUF][4][UCH][XSTR];
    __shared__ _Float16 hbuf[2][4][CSTR];
    for (int i = tid; i < (2 * 4 * CSTR) / 2; i += 512) ((unsigned int*)hbuf)[i] = 0u;

    const int w   = wv;
    const int ch  = (m & 1) | (((m >> 3) & 1) << 1);
    const int ubo = (m >> 1) & 3;
    const int uo  = w * 16 + ubo * 4 + q;
    half8 Ah[4][2];
    const int pw = wv - 4;
    half8 Bg[4][4];
    float bvj[4];

    if (isCons) {
#pragma unroll
        for (int ub = 0; ub < 4; ++ub) {
            const int wrow = (m & 3) * 64 + (w * 16 + ub * 4 + (m >> 2));
#pragma unroll
            for (int s2 = 0; s2 < 2; ++s2) {
                const float* src = Whh + wrow * 64 + s2 * 32 + q * 8;
                half8 tmp;
#pragma unroll
                for (int j = 0; j < 8; ++j) tmp[j] = (_Float16)src[j];
                Ah[ub][s2] = tmp;
            }
        }
    } else {
#pragma unroll
        for (int j = 0; j < 4; ++j) {
            const int n  = pw * 64 + j * 16 + m;
            const int gr = (n & 3) * 64 + (n >> 2);
            bvj[j] = bia[gr];
#pragma unroll
            for (int k4 = 0; k4 < 4; ++k4) {
                const float* src = Wih + gr * 128 + k4 * 32 + q * 8;
                half8 tmp;
#pragma unroll
                for (int jj = 0; jj < 8; ++jj) tmp[jj] = (_Float16)src[jj];
                Bg[j][k4] = tmp;
            }
        }
        half8 pa0, pa1, pa2, pa3;
#pragma unroll
        for (int cb = 0; cb < 2; ++cb) {
            for (int un = 0; un < 16; ++un) {
                int cc = un >> 2, j = un & 3;
                if (j == 0) {
                    int step = cb * UCH + (m & 7);
                    int tA = dir ? (TT - 1 - step) : step;
                    const _Float16* arow = out0 + ((size_t)(b0 + cc) * TT + tA) * 128 + q * 8;
                    pa0 = *(const half8*)(arow);
                    pa1 = *(const half8*)(arow + 32);
                    pa2 = *(const half8*)(arow + 64);
                    pa3 = *(const half8*)(arow + 96);
                }
                f32x4 acc = {bvj[j], bvj[j], bvj[j], bvj[j]};
                acc = __builtin_amdgcn_mfma_f32_16x16x32_f16(pa0, Bg[j][0], acc, 0, 0, 0);
                acc = __builtin_amdgcn_mfma_f32_16x16x32_f16(pa1, Bg[j][1], acc, 0, 0, 0);
                acc = __builtin_amdgcn_mfma_f32_16x16x32_f16(pa2, Bg[j][2], acc, 0, 0, 0);
                acc = __builtin_amdgcn_mfma_f32_16x16x32_f16(pa3, Bg[j][3], acc, 0, 0, 0);
                if (q < 2)
#pragma unroll
                    for (int i = 0; i < 4; ++i)
                        xp[cb][cc][q * 4 + i][pw * 64 + j * 16 + m] = (_Float16)acc[i];
            }
        }
    }
    __syncthreads();

    float c = 0.f, hs = 0.f;
    int p = 0;
    half4 xpre;
    half8 pa0, pa1, pa2, pa3;

    for (int it = 0; it < TT; ++it) {
        if (isCons) {
            const int cck = it >> 3, u = it & 7;
            half4 xvh = (u == 0) ? *(const half4*)&xp[cck % 3][ch][0][uo * 4] : xpre;
            if (u < 7) xpre = *(const half4*)&xp[cck % 3][ch][u + 1][uo * 4];
            f32x4 cin = {(float)xvh[0], (float)xvh[1], (float)xvh[2], (float)xvh[3]};

            half8 ah0 = *(const half8*)&hbuf[p][ch][q * 8];
            half8 ah1 = *(const half8*)&hbuf[p][ch][32 + q * 8];

            f32x4 g_own;
#pragma unroll
            for (int ub = 0; ub < 4; ++ub) {
                f32x4 a = __builtin_amdgcn_mfma_f32_16x16x32_f16(Ah[ub][0], ah0, cin, 0, 0, 0);
                a       = __builtin_amdgcn_mfma_f32_16x16x32_f16(Ah[ub][1], ah1, a, 0, 0, 0);
                if (ub == ubo) g_own = a;
            }

            float e_i = sigm(g_own[0]), e_f = sigm(g_own[1]);
            float e_g = tanh_fast(g_own[2]), e_o = sigm(g_own[3]);
            c = e_f * c + e_i * e_g;
            float hh = e_o * tanh_fast(c);
            hs += hh;

            hbuf[p ^ 1][ch][uo] = (_Float16)hh;
            p ^= 1;
        } else {
            const int cb = (it >> 3) + 2, s = it & 7;
            if (cb < TT / UCH) {
#pragma unroll
                for (int t2 = 0; t2 < 2; ++t2) {
                    int un = s * 2 + t2;
                    int cc = un >> 2, j = un & 3;
                    if (j == 0) {
                        int step = cb * UCH + (m & 7);
                        int tA = dir ? (TT - 1 - step) : step;
                        const _Float16* arow = out0 + ((size_t)(b0 + cc) * TT + tA) * 128 + q * 8;
                        pa0 = *(const half8*)(arow);
                        pa1 = *(const half8*)(arow + 32);
                        pa2 = *(const half8*)(arow + 64);
                        pa3 = *(const half8*)(arow + 96);
                    }
                    f32x4 acc = {bvj[j], bvj[j], bvj[j], bvj[j]};
                    acc = __builtin_amdgcn_mfma_f32_16x16x32_f16(pa0, Bg[j][0], acc, 0, 0, 0);
                    acc = __builtin_amdgcn_mfma_f32_16x16x32_f16(pa1, Bg[j][1], acc, 0, 0, 0);
                    acc = __builtin_amdgcn_mfma_f32_16x16x32_f16(pa2, Bg[j][2], acc, 0, 0, 0);
                    acc = __builtin_amdgcn_mfma_f32_16x16x32_f16(pa3, Bg[j][3], acc, 0, 0, 0);
                    if (q < 2)
#pragma unroll
                        for (int i = 0; i < 4; ++i)
                            xp[cb % 3][cc][q * 4 + i][pw * 64 + j * 16 + m] = (_Float16)acc[i];
                }
            }
        }
        __syncthreads();
    }

    if (isCons) pooled[(size_t)(b0 + ch) * 128 + dir * 64 + uo] = hs;
}

// ---------------------------------------------------------------------------
// Head: out[b] = dot(pooled[b], fcw) / T + fcb
// ---------------------------------------------------------------------------
__global__ __launch_bounds__(64) void fc_head(
    const float* __restrict__ pooled,
    const float* __restrict__ fcw, const float* __restrict__ fcb,
    float* __restrict__ out)
{
    const int b = blockIdx.x;
    const int l = threadIdx.x;
    float v = pooled[b * 128 + l] * fcw[l] + pooled[b * 128 + 64 + l] * fcw[64 + l];
#pragma unroll
    for (int o = 32; o > 0; o >>= 1) v += __shfl_down(v, o);
    if (l == 0) out[b] = v * (1.f / (float)TT) + fcb[0];
}

extern "C" void kernel_launch(void* const* d_in, const int* in_sizes, int n_in,
                              void* d_out, int out_size, void* d_ws, size_t ws_size,
                              hipStream_t stream) {
    const float* x       = (const float*)d_in[0];
    const float* Wih_l0f = (const float*)d_in[1];
    const float* Whh_l0f = (const float*)d_in[2];
    const float* b_l0f   = (const float*)d_in[3];
    const float* Wih_l0b = (const float*)d_in[4];
    const float* Whh_l0b = (const float*)d_in[5];
    const float* b_l0b   = (const float*)d_in[6];
    const float* Wih_l1f = (const float*)d_in[7];
    const float* Whh_l1f = (const float*)d_in[8];
    const float* b_l1f   = (const float*)d_in[9];
    const float* Wih_l1b = (const float*)d_in[10];
    const float* Whh_l1b = (const float*)d_in[11];
    const float* b_l1b   = (const float*)d_in[12];
    const float* fcw     = (const float*)d_in[13];
    const float* fcb     = (const float*)d_in[14];

    const size_t o_xpad   = 0;
    const size_t o_out0   = o_xpad + (size_t)BB * TT * 32 * 2;
    const size_t o_pooled = o_out0 + (size_t)BB * TT * 128 * 2;

    _Float16* xpad   = (_Float16*)((char*)d_ws + o_xpad);
    _Float16* out0   = (_Float16*)((char*)d_ws + o_out0);
    float*    pooled = (float*)((char*)d_ws + o_pooled);

    xpad_prep<<<(BB * TT * 4) / 256, 256, 0, stream>>>(x, xpad);
    lstm_l0<<<(BB / 4) * 2, 512, 0, stream>>>(xpad, Wih_l0f, Whh_l0f, b_l0f,
                                              Wih_l0b, Whh_l0b, b_l0b, out0);
    lstm_l1<<<(BB / 4) * 2, 512, 0, stream>>>(out0, Wih_l1f, Whh_l1f, b_l1f,
                                              Wih_l1b, Whh_l1b, b_l1b, pooled);
    fc_head<<<BB, 64, 0, stream>>>(pooled, fcw, fcb, (float*)d_out);
}